// Round 7
// baseline (169.554 us; speedup 1.0000x reference)
//
#include <hip/hip_runtime.h>
#include <hip/hip_bf16.h>

typedef __bf16 bf16x8 __attribute__((ext_vector_type(8)));
typedef __bf16 bf16x4 __attribute__((ext_vector_type(4)));
typedef float f32x4 __attribute__((ext_vector_type(4)));
typedef unsigned u32x2 __attribute__((ext_vector_type(2)));
typedef unsigned u32x4 __attribute__((ext_vector_type(4)));

#define B_ 2
#define S_ 2048
#define D_ 1024
#define H_ 16
#define HD_ 64
#define NT_ (S_ / 64)   // 32 k-tiles in attn

__device__ inline void load_lds16(const __bf16* g, __bf16* l) {
  __builtin_amdgcn_global_load_lds(
      (const __attribute__((address_space(1))) void*)g,
      (__attribute__((address_space(3))) void*)l, 16, 0, 0);
}

// ---------------------------------------------------------------------------
// prep: z<3  -> transpose+convert W_z (fp32 [k][n]) to bf16 WT[z][n][k]
//       z==3 -> convert X fp32 -> bf16 (same layout)
// ---------------------------------------------------------------------------
__global__ __launch_bounds__(256) void prep(
    const float* __restrict__ X,
    const float* __restrict__ Wq, const float* __restrict__ Wk,
    const float* __restrict__ Wv,
    __bf16* __restrict__ Xb, __bf16* __restrict__ WT)
{
  const int z = blockIdx.z, t = threadIdx.x;
  if (z == 3) {
    size_t base = ((size_t)(blockIdx.y * 16 + blockIdx.x)) * 16384 + t * 4;
#pragma unroll
    for (int i = 0; i < 16; ++i) {
      size_t idx = base + (size_t)i * 1024;
      f32x4 v = *(const f32x4*)(X + idx);
      __bf16 o[4];
#pragma unroll
      for (int j = 0; j < 4; ++j) o[j] = (__bf16)v[j];
      *(ulong1*)(Xb + idx) = *(ulong1*)o;
    }
    return;
  }
  const float* W = (z == 0) ? Wq : (z == 1) ? Wk : Wv;
  __bf16* WTz = WT + (size_t)z * D_ * D_;
  const int k0 = blockIdx.y * 64, n0 = blockIdx.x * 64;

  __shared__ __bf16 T[64 * 72];
  {
    int kl = t >> 2, cg = (t & 3) * 16;
    const float* wp = W + (size_t)(k0 + kl) * D_ + n0 + cg;
    bf16x8 a, b;
#pragma unroll
    for (int j = 0; j < 4; ++j) { a[j] = (__bf16)wp[j];     a[4 + j] = (__bf16)wp[4 + j]; }
#pragma unroll
    for (int j = 0; j < 4; ++j) { b[j] = (__bf16)wp[8 + j]; b[4 + j] = (__bf16)wp[12 + j]; }
    *(bf16x8*)(T + kl * 72 + cg) = a;
    *(bf16x8*)(T + kl * 72 + cg + 8) = b;
  }
  __syncthreads();
  {
    int nl = t >> 2, kc = (t & 3) * 16;
    bf16x8 a, b;
#pragma unroll
    for (int j = 0; j < 8; ++j) a[j] = T[(kc + j) * 72 + nl];
#pragma unroll
    for (int j = 0; j < 8; ++j) b[j] = T[(kc + 8 + j) * 72 + nl];
    __bf16* op = WTz + (size_t)(n0 + nl) * D_ + k0 + kc;
    *(bf16x8*)(op) = a;
    *(bf16x8*)(op + 8) = b;
  }
}

// ---------------------------------------------------------------------------
// QKV projection v2: m97 structure with BK=64 (one barrier pair per 64 K
// instead of per 32 -> half the barrier/drain convoys). Staging + read use
// attn's proven 64-wide-row pattern: linear LDS dest, source chunk
// pre-swizzled (cc^(row&7)), read de-swizzled ((ks*4+quad)^(ln&7)) -> 2-way
// bank aliasing only (free). Frags loaded per-ks -> register pressure
// unchanged vs BK=32.
//   z==0: Q (*0.125*log2e), z==1: K, z==2: V stored transposed VT[b][n][s]
// ---------------------------------------------------------------------------
__global__ __launch_bounds__(256) void qkv_gemm(
    const __bf16* __restrict__ Xb, const __bf16* __restrict__ WT,
    const float* __restrict__ bq, const float* __restrict__ bk,
    const float* __restrict__ bv,
    __bf16* __restrict__ Qw, __bf16* __restrict__ Kw, __bf16* __restrict__ VTw)
{
  const int z = blockIdx.z;
  const __bf16* Wz = WT + (size_t)z * D_ * D_;
  const float* bias = (z == 0) ? bq : (z == 1) ? bk : bv;
  __bf16* outp = (z == 0) ? Qw : (z == 1) ? Kw : VTw;
  const float mult = (z == 0) ? 0.125f * 1.44269504088896f : 1.0f;

  const int tid  = threadIdx.x;
  const int wave = tid >> 6, lane = tid & 63, ln = lane & 15, quad = lane >> 4;
  const int m0 = blockIdx.y * 128, n0 = blockIdx.x * 128;
  const int wm = (wave & 1) * 64, wn = (wave >> 1) * 64;

  __shared__ __bf16 Als[128 * 64];   // 16 KB, rows of 64 bf16 (8 chunks)
  __shared__ __bf16 Bls[128 * 64];   // 16 KB

  f32x4 acc[4][4] = {};

  for (int k0 = 0; k0 < D_; k0 += 64) {
    __syncthreads();
#pragma unroll
    for (int i = 0; i < 4; ++i) {
      int cb = wave * 256 + i * 64;          // wave-uniform chunk base
      int chunk = cb + lane;
      int row = chunk >> 3, cc = chunk & 7;
      int gc = (cc ^ (row & 7)) * 8;         // pre-swizzled global source
      load_lds16(Xb + (size_t)(m0 + row) * D_ + k0 + gc, Als + cb * 8);
      load_lds16(Wz + (size_t)(n0 + row) * D_ + k0 + gc, Bls + cb * 8);
    }
    __syncthreads();

#pragma unroll
    for (int ks = 0; ks < 2; ++ks) {
      bf16x8 af[4], bfr[4];
      const int dsw = ((ks * 4 + quad) ^ (ln & 7)) * 8;   // de-swizzle (row&7==ln&7)
#pragma unroll
      for (int mt = 0; mt < 4; ++mt)
        af[mt] = *(const bf16x8*)(Als + (wm + mt * 16 + ln) * 64 + dsw);
#pragma unroll
      for (int nt = 0; nt < 4; ++nt)
        bfr[nt] = *(const bf16x8*)(Bls + (wn + nt * 16 + ln) * 64 + dsw);
#pragma unroll
      for (int mt = 0; mt < 4; ++mt)
#pragma unroll
        for (int nt = 0; nt < 4; ++nt)
          acc[mt][nt] = __builtin_amdgcn_mfma_f32_16x16x32_bf16(af[mt], bfr[nt], acc[mt][nt], 0, 0, 0);
    }
  }

#pragma unroll
  for (int nt = 0; nt < 4; ++nt) {
    int n_g = n0 + wn + nt * 16 + ln;
    float bv_ = bias[n_g];
#pragma unroll
    for (int mt = 0; mt < 4; ++mt) {
      if (z < 2) {
#pragma unroll
        for (int r = 0; r < 4; ++r) {
          int m_g = m0 + wm + mt * 16 + quad * 4 + r;
          outp[(size_t)m_g * D_ + n_g] = (__bf16)((acc[mt][nt][r] + bv_) * mult);
        }
      } else {
        // VT[b][n][s]: pack r (4 consecutive s) into one b64 store
        int m_g0 = m0 + wm + mt * 16 + quad * 4;
        bf16x4 v4;
#pragma unroll
        for (int r = 0; r < 4; ++r) v4[r] = (__bf16)(acc[mt][nt][r] + bv_);
        *(bf16x4*)(outp + (size_t)(m_g0 >> 11) * D_ * S_ + (size_t)n_g * S_ + (m_g0 & (S_ - 1))) = v4;
      }
    }
  }
}

// ---------------------------------------------------------------------------
// Flash attention v8 (R4, proven 45.0 us): reg-prefetch staging, XOR-swizzled
// K/V LDS, single barrier/tile, lagged PV (PV(t-1) inside QK(t)'s MFMA
// cluster from register banks), in-register permlane P reshuffle,
// unnormalized exp2 softmax with MFMA row-sums (ones B-operand in regs).
// ---------------------------------------------------------------------------
__global__ __launch_bounds__(256) void attn(
    const __bf16* __restrict__ Q, const __bf16* __restrict__ K,
    const __bf16* __restrict__ VT, float* __restrict__ out)
{
  const int tid  = threadIdx.x;
  const int wave = tid >> 6, lane = tid & 63, ln = lane & 15, quad = lane >> 4;

  const int f = blockIdx.x;
  const int xcd = f & 7, g = f >> 3;
  const int bh = ((g & 3) << 3) | xcd;   // 4 bh per XCD -> K/V L2-resident
  const int qt = g >> 2;                 // 0..15
  const int b = bh >> 4, h = bh & 15;
  const int q0 = qt * 128 + wave * 32;

  // Q B-frags (regs for whole kernel): lane n=ln -> q row, k = ks*32+quad*8+j
  const __bf16* Qbase = Q + (size_t)(b * S_ + q0) * D_ + h * HD_;
  bf16x8 qb[2][2];
#pragma unroll
  for (int nt = 0; nt < 2; ++nt)
#pragma unroll
    for (int ks = 0; ks < 2; ++ks)
      qb[nt][ks] = *(const bf16x8*)(Qbase + (size_t)(nt * 16 + ln) * D_ + ks * 32 + quad * 8);

  const __bf16* Kh = K + (size_t)b * S_ * D_ + h * HD_;        // [key][d]
  const __bf16* Vh = VT + (size_t)(b * D_ + h * HD_) * S_;     // [d][s]

  __shared__ __bf16 Kls[2][64 * 64];   // [key][d], swizzled chunks
  __shared__ __bf16 Vls[2][64 * 64];   // [d][key], swizzled chunks

  bf16x8 vones;
#pragma unroll
  for (int j = 0; j < 8; ++j) vones[j] = (__bf16)1.0f;

  f32x4 acc[2][5] = {};                // [q-block][d-tile 0..3, 4 = row-sum]
  const int swl = ln & 7;              // read-side swizzle key

  // prefetch tile 0 (2 chunks K + 2 chunks V per thread)
  bf16x8 kreg[2], vreg[2];
#pragma unroll
  for (int i = 0; i < 2; ++i) {
    int chunk = i * 256 + tid, row = chunk >> 3, cc = chunk & 7;
    kreg[i] = *(const bf16x8*)(Kh + (size_t)row * D_ + cc * 8);
    vreg[i] = *(const bf16x8*)(Vh + (size_t)row * S_ + cc * 8);
  }

  bf16x8 vfrA[4][2], vfrB[4][2];       // V frag banks (register)
  bf16x8 paA[2][2], paB[2][2];         // P A-frag banks (register)

  // one pipeline slot: stage tile KT_, prefetch KT_+1, barrier, hoist V(KT_)
  // frags into bank VN, QK(KT_) -> st, PV(KT_-1) from {PAP, VP}, exp2 -> PAN
#define SLOT(KT_, VN, VP, PAN, PAP, DO_PV)                                     \
  {                                                                            \
    const int bi = (KT_) & 1;                                                  \
    __bf16* Kb = Kls[bi];                                                      \
    __bf16* Vb = Vls[bi];                                                      \
    _Pragma("unroll")                                                          \
    for (int i = 0; i < 2; ++i) {                                              \
      int chunk = i * 256 + tid, row = chunk >> 3, cc = chunk & 7;             \
      int sw = (cc ^ (row & 7)) * 8;                                           \
      *(bf16x8*)(Kb + row * 64 + sw) = kreg[i];                                \
      *(bf16x8*)(Vb + row * 64 + sw) = vreg[i];                                \
    }                                                                          \
    if ((KT_) + 1 < NT_) {                                                     \
      _Pragma("unroll")                                                        \
      for (int i = 0; i < 2; ++i) {                                            \
        int chunk = i * 256 + tid, row = chunk >> 3, cc = chunk & 7;           \
        kreg[i] = *(const bf16x8*)(Kh + (size_t)(((KT_) + 1) * 64 + row) * D_ + cc * 8); \
        vreg[i] = *(const bf16x8*)(Vh + (size_t)row * S_ + ((KT_) + 1) * 64 + cc * 8);   \
      }                                                                        \
    }                                                                          \
    __syncthreads();                                                           \
    _Pragma("unroll")                                                          \
    for (int dt = 0; dt < 4; ++dt)                                             \
      _Pragma("unroll")                                                        \
      for (int ks = 0; ks < 2; ++ks)                                           \
        VN[dt][ks] = *(const bf16x8*)(Vb + (dt * 16 + ln) * 64 + ((ks * 4 + quad) ^ swl) * 8); \
    f32x4 st[4][2] = {};                                                       \
    __builtin_amdgcn_s_setprio(1);                                             \
    _Pragma("unroll")                                                          \
    for (int mt = 0; mt < 4; ++mt)                                             \
      _Pragma("unroll")                                                        \
      for (int ks = 0; ks < 2; ++ks) {                                         \
        bf16x8 ka = *(const bf16x8*)(Kb + (mt * 16 + ln) * 64 + ((ks * 4 + quad) ^ swl) * 8); \
        _Pragma("unroll")                                                      \
        for (int nt = 0; nt < 2; ++nt)                                         \
          st[mt][nt] = __builtin_amdgcn_mfma_f32_16x16x32_bf16(ka, qb[nt][ks], st[mt][nt], 0, 0, 0); \
      }                                                                        \
    if (DO_PV) {                                                               \
      _Pragma("unroll")                                                        \
      for (int ks = 0; ks < 2; ++ks)                                           \
        _Pragma("unroll")                                                      \
        for (int dt = 0; dt < 5; ++dt) {                                       \
          bf16x8 vb = (dt < 4) ? VP[dt][ks] : vones;                           \
          _Pragma("unroll")                                                    \
          for (int nt = 0; nt < 2; ++nt)                                       \
            acc[nt][dt] = __builtin_amdgcn_mfma_f32_16x16x32_bf16(PAP[nt][ks], vb, acc[nt][dt], 0, 0, 0); \
        }                                                                      \
    }                                                                          \
    __builtin_amdgcn_s_setprio(0);                                             \
    _Pragma("unroll")                                                          \
    for (int nt = 0; nt < 2; ++nt)                                             \
      _Pragma("unroll")                                                        \
      for (int ks = 0; ks < 2; ++ks) {                                         \
        bf16x4 p0, p1;                                                         \
        _Pragma("unroll")                                                      \
        for (int r = 0; r < 4; ++r) {                                          \
          p0[r] = (__bf16)__builtin_amdgcn_exp2f(st[2 * ks + 0][nt][r]);       \
          p1[r] = (__bf16)__builtin_amdgcn_exp2f(st[2 * ks + 1][nt][r]);       \
        }                                                                      \
        u32x2 d0 = __builtin_bit_cast(u32x2, p0);                              \
        u32x2 d1 = __builtin_bit_cast(u32x2, p1);                              \
        unsigned a = d0[0], bw = d0[1], c = d1[0], e = d1[1];                  \
        asm("v_permlane32_swap_b32 %0, %1" : "+v"(a), "+v"(c));                \
        asm("v_permlane16_swap_b32 %0, %1" : "+v"(a), "+v"(c));                \
        asm("v_permlane32_swap_b32 %0, %1" : "+v"(bw), "+v"(e));               \
        asm("v_permlane16_swap_b32 %0, %1" : "+v"(bw), "+v"(e));               \
        u32x4 w;                                                               \
        w[0] = a; w[1] = bw; w[2] = c; w[3] = e;                               \
        PAN[nt][ks] = __builtin_bit_cast(bf16x8, w);                           \
      }                                                                        \
  }

  for (int kt = 0; kt < NT_; kt += 2) {
    SLOT(kt,     vfrA, vfrB, paA, paB, kt > 0);   // PV(kt-1) from B banks
    SLOT(kt + 1, vfrB, vfrA, paB, paA, 1);        // PV(kt)   from A banks
  }
#undef SLOT

  // drain: PV for tile NT_-1 (banks B)
#pragma unroll
  for (int ks = 0; ks < 2; ++ks)
#pragma unroll
    for (int dt = 0; dt < 5; ++dt) {
      bf16x8 vb = (dt < 4) ? vfrB[dt][ks] : vones;
#pragma unroll
      for (int nt = 0; nt < 2; ++nt)
        acc[nt][dt] = __builtin_amdgcn_mfma_f32_16x16x32_bf16(paB[nt][ks], vb, acc[nt][dt], 0, 0, 0);
    }

  // acc[nt][4][r] = row sum (identical across ln); normalize + store fp32
#pragma unroll
  for (int nt = 0; nt < 2; ++nt)
#pragma unroll
    for (int r = 0; r < 4; ++r) {
      float li = 1.0f / acc[nt][4][r];
      float* op = out + (size_t)(b * S_ + q0 + nt * 16 + quad * 4 + r) * D_ + h * HD_;
#pragma unroll
      for (int dt = 0; dt < 4; ++dt)
        op[dt * 16 + ln] = acc[nt][dt][r] * li;
    }
}

extern "C" void kernel_launch(void* const* d_in, const int* in_sizes, int n_in,
                              void* d_out, int out_size, void* d_ws, size_t ws_size,
                              hipStream_t stream) {
  const float* X  = (const float*)d_in[0];
  const float* Wq = (const float*)d_in[1];
  const float* bq = (const float*)d_in[2];
  const float* Wk = (const float*)d_in[3];
  const float* bk = (const float*)d_in[4];
  const float* Wv = (const float*)d_in[5];
  const float* bv = (const float*)d_in[6];

  __bf16* Qw  = (__bf16*)d_ws;                        // 8 MB
  __bf16* Kw  = Qw  + (size_t)B_ * S_ * D_;           // 8 MB
  __bf16* VTw = Kw  + (size_t)B_ * S_ * D_;           // 8 MB
  __bf16* Xb  = VTw + (size_t)B_ * S_ * D_;           // 8 MB
  __bf16* WT  = Xb  + (size_t)B_ * S_ * D_;           // 6 MB
  float* out = (float*)d_out;

  prep<<<dim3(16, 16, 4), 256, 0, stream>>>(X, Wq, Wk, Wv, Xb, WT);
  qkv_gemm<<<dim3(8, 32, 3), 256, 0, stream>>>(Xb, WT, bq, bk, bv, Qw, Kw, VTw);
  attn<<<512, 256, 0, stream>>>(Qw, Kw, VTw, out);
}

// Round 10
// 169.208 us; speedup vs baseline: 1.0020x; 1.0020x over previous
//
#include <hip/hip_runtime.h>
#include <hip/hip_bf16.h>

typedef __bf16 bf16x8 __attribute__((ext_vector_type(8)));
typedef __bf16 bf16x4 __attribute__((ext_vector_type(4)));
typedef float f32x4 __attribute__((ext_vector_type(4)));
typedef unsigned u32x2 __attribute__((ext_vector_type(2)));
typedef unsigned u32x4 __attribute__((ext_vector_type(4)));

#define B_ 2
#define S_ 2048
#define D_ 1024
#define H_ 16
#define HD_ 64
#define NT_ (S_ / 64)   // 32 k-tiles in attn

__device__ inline void load_lds16(const __bf16* g, __bf16* l) {
  __builtin_amdgcn_global_load_lds(
      (const __attribute__((address_space(1))) void*)g,
      (__attribute__((address_space(3))) void*)l, 16, 0, 0);
}

// ---------------------------------------------------------------------------
// prep: z<3  -> transpose+convert W_z (fp32 [k][n]) to bf16 WT[z][n][k]
//       z==3 -> convert X fp32 -> bf16 (same layout)
// ---------------------------------------------------------------------------
__global__ __launch_bounds__(256) void prep(
    const float* __restrict__ X,
    const float* __restrict__ Wq, const float* __restrict__ Wk,
    const float* __restrict__ Wv,
    __bf16* __restrict__ Xb, __bf16* __restrict__ WT)
{
  const int z = blockIdx.z, t = threadIdx.x;
  if (z == 3) {
    size_t base = ((size_t)(blockIdx.y * 16 + blockIdx.x)) * 16384 + t * 4;
#pragma unroll
    for (int i = 0; i < 16; ++i) {
      size_t idx = base + (size_t)i * 1024;
      f32x4 v = *(const f32x4*)(X + idx);
      __bf16 o[4];
#pragma unroll
      for (int j = 0; j < 4; ++j) o[j] = (__bf16)v[j];
      *(ulong1*)(Xb + idx) = *(ulong1*)o;
    }
    return;
  }
  const float* W = (z == 0) ? Wq : (z == 1) ? Wk : Wv;
  __bf16* WTz = WT + (size_t)z * D_ * D_;
  const int k0 = blockIdx.y * 64, n0 = blockIdx.x * 64;

  __shared__ __bf16 T[64 * 72];
  {
    int kl = t >> 2, cg = (t & 3) * 16;
    const float* wp = W + (size_t)(k0 + kl) * D_ + n0 + cg;
    bf16x8 a, b;
#pragma unroll
    for (int j = 0; j < 4; ++j) { a[j] = (__bf16)wp[j];     a[4 + j] = (__bf16)wp[4 + j]; }
#pragma unroll
    for (int j = 0; j < 4; ++j) { b[j] = (__bf16)wp[8 + j]; b[4 + j] = (__bf16)wp[12 + j]; }
    *(bf16x8*)(T + kl * 72 + cg) = a;
    *(bf16x8*)(T + kl * 72 + cg + 8) = b;
  }
  __syncthreads();
  {
    int nl = t >> 2, kc = (t & 3) * 16;
    bf16x8 a, b;
#pragma unroll
    for (int j = 0; j < 8; ++j) a[j] = T[(kc + j) * 72 + nl];
#pragma unroll
    for (int j = 0; j < 8; ++j) b[j] = T[(kc + 8 + j) * 72 + nl];
    __bf16* op = WTz + (size_t)(n0 + nl) * D_ + k0 + kc;
    *(bf16x8*)(op) = a;
    *(bf16x8*)(op + 8) = b;
  }
}

// ---------------------------------------------------------------------------
// QKV projection (m97 structure + XOR-swizzled LDS, BK=32 — proven).
//   z==0: Q (*0.125*log2e), z==1: K, z==2: V stored transposed VT[b][n][s]
// ---------------------------------------------------------------------------
__global__ __launch_bounds__(256) void qkv_gemm(
    const __bf16* __restrict__ Xb, const __bf16* __restrict__ WT,
    const float* __restrict__ bq, const float* __restrict__ bk,
    const float* __restrict__ bv,
    __bf16* __restrict__ Qw, __bf16* __restrict__ Kw, __bf16* __restrict__ VTw)
{
  const int z = blockIdx.z;
  const __bf16* Wz = WT + (size_t)z * D_ * D_;
  const float* bias = (z == 0) ? bq : (z == 1) ? bk : bv;
  __bf16* outp = (z == 0) ? Qw : (z == 1) ? Kw : VTw;
  const float mult = (z == 0) ? 0.125f * 1.44269504088896f : 1.0f;

  const int tid  = threadIdx.x;
  const int wave = tid >> 6, lane = tid & 63, ln = lane & 15, quad = lane >> 4;
  const int m0 = blockIdx.y * 128, n0 = blockIdx.x * 128;
  const int wm = (wave & 1) * 64, wn = (wave >> 1) * 64;

  __shared__ __bf16 Als[128 * 32];
  __shared__ __bf16 Bls[128 * 32];

  f32x4 acc[4][4] = {};

  for (int k0 = 0; k0 < D_; k0 += 32) {
    __syncthreads();
#pragma unroll
    for (int i = 0; i < 2; ++i) {
      int cb = wave * 128 + i * 64;          // wave-uniform chunk base
      int chunk = cb + lane;
      int row = chunk >> 2, c = chunk & 3;
      int gc = c ^ (row & 3);                // swizzled global source chunk
      load_lds16(Xb + (size_t)(m0 + row) * D_ + k0 + gc * 8, Als + cb * 8);
      load_lds16(Wz + (size_t)(n0 + row) * D_ + k0 + gc * 8, Bls + cb * 8);
    }
    __syncthreads();

    bf16x8 af[4], bfr[4];
    const int dsw = (quad ^ (ln & 3)) * 8;   // de-swizzle (row&3 == ln&3)
#pragma unroll
    for (int mt = 0; mt < 4; ++mt)
      af[mt] = *(const bf16x8*)(Als + (wm + mt * 16 + ln) * 32 + dsw);
#pragma unroll
    for (int nt = 0; nt < 4; ++nt)
      bfr[nt] = *(const bf16x8*)(Bls + (wn + nt * 16 + ln) * 32 + dsw);
#pragma unroll
    for (int mt = 0; mt < 4; ++mt)
#pragma unroll
      for (int nt = 0; nt < 4; ++nt)
        acc[mt][nt] = __builtin_amdgcn_mfma_f32_16x16x32_bf16(af[mt], bfr[nt], acc[mt][nt], 0, 0, 0);
  }

#pragma unroll
  for (int nt = 0; nt < 4; ++nt) {
    int n_g = n0 + wn + nt * 16 + ln;
    float bv_ = bias[n_g];
#pragma unroll
    for (int mt = 0; mt < 4; ++mt) {
      if (z < 2) {
#pragma unroll
        for (int r = 0; r < 4; ++r) {
          int m_g = m0 + wm + mt * 16 + quad * 4 + r;
          outp[(size_t)m_g * D_ + n_g] = (__bf16)((acc[mt][nt][r] + bv_) * mult);
        }
      } else {
        // VT[b][n][s]: pack r (4 consecutive s) into one b64 store
        int m_g0 = m0 + wm + mt * 16 + quad * 4;
        bf16x4 v4;
#pragma unroll
        for (int r = 0; r < 4; ++r) v4[r] = (__bf16)(acc[mt][nt][r] + bv_);
        *(bf16x4*)(outp + (size_t)(m_g0 >> 11) * D_ * S_ + (size_t)n_g * S_ + (m_g0 & (S_ - 1))) = v4;
      }
    }
  }
}

// ---------------------------------------------------------------------------
// Flash attention v13 = v8 (proven: reg staging, XOR-swizzled K/V LDS, one
// barrier/tile, lagged PV, permlane P reshuffle, unnormalized exp2 softmax
// with MFMA row-sums) with ONE data-identical change: register prefetch
// depth 1 -> 2 (banks KA/KB via static names). Global loads for tile t+2
// issue at slot t, consumed (ds_write) at slot t+2 -> ~2 slots of latency
// slack instead of 1. Staged bytes, LDS addresses, barriers, and all compute
// are bit-identical to v8; only load issue time moves earlier. Registers are
// lane-private -> no new ordering surface.
// Structure edits beyond this are frozen: R5/R8/R9 all failed numerically.
// ---------------------------------------------------------------------------
__global__ __launch_bounds__(256) void attn(
    const __bf16* __restrict__ Q, const __bf16* __restrict__ K,
    const __bf16* __restrict__ VT, float* __restrict__ out)
{
  const int tid  = threadIdx.x;
  const int wave = tid >> 6, lane = tid & 63, ln = lane & 15, quad = lane >> 4;

  const int f = blockIdx.x;
  const int xcd = f & 7, g = f >> 3;
  const int bh = ((g & 3) << 3) | xcd;   // 4 bh per XCD -> K/V L2-resident
  const int qt = g >> 2;                 // 0..15
  const int b = bh >> 4, h = bh & 15;
  const int q0 = qt * 128 + wave * 32;

  // Q B-frags (regs for whole kernel): lane n=ln -> q row, k = ks*32+quad*8+j
  const __bf16* Qbase = Q + (size_t)(b * S_ + q0) * D_ + h * HD_;
  bf16x8 qb[2][2];
#pragma unroll
  for (int nt = 0; nt < 2; ++nt)
#pragma unroll
    for (int ks = 0; ks < 2; ++ks)
      qb[nt][ks] = *(const bf16x8*)(Qbase + (size_t)(nt * 16 + ln) * D_ + ks * 32 + quad * 8);

  const __bf16* Kh = K + (size_t)b * S_ * D_ + h * HD_;        // [key][d]
  const __bf16* Vh = VT + (size_t)(b * D_ + h * HD_) * S_;     // [d][s]

  __shared__ __bf16 Kls[2][64 * 64];   // [key][d], swizzled chunks
  __shared__ __bf16 Vls[2][64 * 64];   // [d][key], swizzled chunks

  bf16x8 vones;
#pragma unroll
  for (int j = 0; j < 8; ++j) vones[j] = (__bf16)1.0f;

  f32x4 acc[2][5] = {};                // [q-block][d-tile 0..3, 4 = row-sum]
  const int swl = ln & 7;              // read-side swizzle key

  // 2-deep register prefetch banks: KA/VA hold even tiles, KB/VB odd tiles.
  bf16x8 kregA[2], vregA[2], kregB[2], vregB[2];
#pragma unroll
  for (int i = 0; i < 2; ++i) {
    int chunk = i * 256 + tid, row = chunk >> 3, cc = chunk & 7;
    kregA[i] = *(const bf16x8*)(Kh + (size_t)row * D_ + cc * 8);
    vregA[i] = *(const bf16x8*)(Vh + (size_t)row * S_ + cc * 8);
    kregB[i] = *(const bf16x8*)(Kh + (size_t)(64 + row) * D_ + cc * 8);
    vregB[i] = *(const bf16x8*)(Vh + (size_t)row * S_ + 64 + cc * 8);
  }

  bf16x8 vfrA[4][2], vfrB[4][2];       // V frag banks (register)
  bf16x8 paA[2][2], paB[2][2];         // P A-frag banks (register)

  // one pipeline slot: ds_write tile KT_ from bank {KRG,VRG}, reload that
  // bank with tile KT_+2, barrier, hoist V(KT_) frags into VN, QK(KT_) ->
  // st, PV(KT_-1) from {PAP, VP}, exp2 -> PAN
#define SLOT(KT_, KRG, VRG, VN, VP, PAN, PAP, DO_PV)                           \
  {                                                                            \
    const int bi = (KT_) & 1;                                                  \
    __bf16* Kb = Kls[bi];                                                      \
    __bf16* Vb = Vls[bi];                                                      \
    _Pragma("unroll")                                                          \
    for (int i = 0; i < 2; ++i) {                                              \
      int chunk = i * 256 + tid, row = chunk >> 3, cc = chunk & 7;             \
      int sw = (cc ^ (row & 7)) * 8;                                           \
      *(bf16x8*)(Kb + row * 64 + sw) = KRG[i];                                 \
      *(bf16x8*)(Vb + row * 64 + sw) = VRG[i];                                 \
    }                                                                          \
    if ((KT_) + 2 < NT_) {                                                     \
      _Pragma("unroll")                                                        \
      for (int i = 0; i < 2; ++i) {                                            \
        int chunk = i * 256 + tid, row = chunk >> 3, cc = chunk & 7;           \
        KRG[i] = *(const bf16x8*)(Kh + (size_t)(((KT_) + 2) * 64 + row) * D_ + cc * 8); \
        VRG[i] = *(const bf16x8*)(Vh + (size_t)row * S_ + ((KT_) + 2) * 64 + cc * 8);   \
      }                                                                        \
    }                                                                          \
    __syncthreads();                                                           \
    _Pragma("unroll")                                                          \
    for (int dt = 0; dt < 4; ++dt)                                             \
      _Pragma("unroll")                                                        \
      for (int ks = 0; ks < 2; ++ks)                                           \
        VN[dt][ks] = *(const bf16x8*)(Vb + (dt * 16 + ln) * 64 + ((ks * 4 + quad) ^ swl) * 8); \
    f32x4 st[4][2] = {};                                                       \
    __builtin_amdgcn_s_setprio(1);                                             \
    _Pragma("unroll")                                                          \
    for (int mt = 0; mt < 4; ++mt)                                             \
      _Pragma("unroll")                                                        \
      for (int ks = 0; ks < 2; ++ks) {                                         \
        bf16x8 ka = *(const bf16x8*)(Kb + (mt * 16 + ln) * 64 + ((ks * 4 + quad) ^ swl) * 8); \
        _Pragma("unroll")                                                      \
        for (int nt = 0; nt < 2; ++nt)                                         \
          st[mt][nt] = __builtin_amdgcn_mfma_f32_16x16x32_bf16(ka, qb[nt][ks], st[mt][nt], 0, 0, 0); \
      }                                                                        \
    if (DO_PV) {                                                               \
      _Pragma("unroll")                                                        \
      for (int ks = 0; ks < 2; ++ks)                                           \
        _Pragma("unroll")                                                      \
        for (int dt = 0; dt < 5; ++dt) {                                       \
          bf16x8 vb = (dt < 4) ? VP[dt][ks] : vones;                           \
          _Pragma("unroll")                                                    \
          for (int nt = 0; nt < 2; ++nt)                                       \
            acc[nt][dt] = __builtin_amdgcn_mfma_f32_16x16x32_bf16(PAP[nt][ks], vb, acc[nt][dt], 0, 0, 0); \
        }                                                                      \
    }                                                                          \
    __builtin_amdgcn_s_setprio(0);                                             \
    _Pragma("unroll")                                                          \
    for (int nt = 0; nt < 2; ++nt)                                             \
      _Pragma("unroll")                                                        \
      for (int ks = 0; ks < 2; ++ks) {                                         \
        bf16x4 p0, p1;                                                         \
        _Pragma("unroll")                                                      \
        for (int r = 0; r < 4; ++r) {                                          \
          p0[r] = (__bf16)__builtin_amdgcn_exp2f(st[2 * ks + 0][nt][r]);       \
          p1[r] = (__bf16)__builtin_amdgcn_exp2f(st[2 * ks + 1][nt][r]);       \
        }                                                                      \
        u32x2 d0 = __builtin_bit_cast(u32x2, p0);                              \
        u32x2 d1 = __builtin_bit_cast(u32x2, p1);                              \
        unsigned a = d0[0], bw = d0[1], c = d1[0], e = d1[1];                  \
        asm("v_permlane32_swap_b32 %0, %1" : "+v"(a), "+v"(c));                \
        asm("v_permlane16_swap_b32 %0, %1" : "+v"(a), "+v"(c));                \
        asm("v_permlane32_swap_b32 %0, %1" : "+v"(bw), "+v"(e));               \
        asm("v_permlane16_swap_b32 %0, %1" : "+v"(bw), "+v"(e));               \
        u32x4 w;                                                               \
        w[0] = a; w[1] = bw; w[2] = c; w[3] = e;                               \
        PAN[nt][ks] = __builtin_bit_cast(bf16x8, w);                           \
      }                                                                        \
  }

  for (int kt = 0; kt < NT_; kt += 2) {
    SLOT(kt,     kregA, vregA, vfrA, vfrB, paA, paB, kt > 0);  // PV(kt-1)
    SLOT(kt + 1, kregB, vregB, vfrB, vfrA, paB, paA, 1);       // PV(kt)
  }
#undef SLOT

  // drain: PV for tile NT_-1 (banks B)
#pragma unroll
  for (int ks = 0; ks < 2; ++ks)
#pragma unroll
    for (int dt = 0; dt < 5; ++dt) {
      bf16x8 vb = (dt < 4) ? vfrB[dt][ks] : vones;
#pragma unroll
      for (int nt = 0; nt < 2; ++nt)
        acc[nt][dt] = __builtin_amdgcn_mfma_f32_16x16x32_bf16(paB[nt][ks], vb, acc[nt][dt], 0, 0, 0);
    }

  // acc[nt][4][r] = row sum (identical across ln); normalize + store fp32
#pragma unroll
  for (int nt = 0; nt < 2; ++nt)
#pragma unroll
    for (int r = 0; r < 4; ++r) {
      float li = 1.0f / acc[nt][4][r];
      float* op = out + (size_t)(b * S_ + q0 + nt * 16 + quad * 4 + r) * D_ + h * HD_;
#pragma unroll
      for (int dt = 0; dt < 4; ++dt)
        op[dt * 16 + ln] = acc[nt][dt][r] * li;
    }
}

extern "C" void kernel_launch(void* const* d_in, const int* in_sizes, int n_in,
                              void* d_out, int out_size, void* d_ws, size_t ws_size,
                              hipStream_t stream) {
  const float* X  = (const float*)d_in[0];
  const float* Wq = (const float*)d_in[1];
  const float* bq = (const float*)d_in[2];
  const float* Wk = (const float*)d_in[3];
  const float* bk = (const float*)d_in[4];
  const float* Wv = (const float*)d_in[5];
  const float* bv = (const float*)d_in[6];

  __bf16* Qw  = (__bf16*)d_ws;                        // 8 MB
  __bf16* Kw  = Qw  + (size_t)B_ * S_ * D_;           // 8 MB
  __bf16* VTw = Kw  + (size_t)B_ * S_ * D_;           // 8 MB
  __bf16* Xb  = VTw + (size_t)B_ * S_ * D_;           // 8 MB
  __bf16* WT  = Xb  + (size_t)B_ * S_ * D_;           // 6 MB
  float* out = (float*)d_out;

  prep<<<dim3(16, 16, 4), 256, 0, stream>>>(X, Wq, Wk, Wv, Xb, WT);
  qkv_gemm<<<dim3(8, 32, 3), 256, 0, stream>>>(Xb, WT, bq, bk, bv, Qw, Kw, VTw);
  attn<<<512, 256, 0, stream>>>(Qw, Kw, VTw, out);
}

// Round 11
// 156.405 us; speedup vs baseline: 1.0841x; 1.0819x over previous
//
#include <hip/hip_runtime.h>
#include <hip/hip_bf16.h>

typedef __bf16 bf16x8 __attribute__((ext_vector_type(8)));
typedef __bf16 bf16x4 __attribute__((ext_vector_type(4)));
typedef float f32x4 __attribute__((ext_vector_type(4)));
typedef unsigned u32x2 __attribute__((ext_vector_type(2)));
typedef unsigned u32x4 __attribute__((ext_vector_type(4)));

#define B_ 2
#define S_ 2048
#define D_ 1024
#define H_ 16
#define HD_ 64
#define NT_ (S_ / 64)   // 32 k-tiles in attn

__device__ inline void load_lds16(const __bf16* g, __bf16* l) {
  __builtin_amdgcn_global_load_lds(
      (const __attribute__((address_space(1))) void*)g,
      (__attribute__((address_space(3))) void*)l, 16, 0, 0);
}

// ---------------------------------------------------------------------------
// prep: z<3  -> transpose+convert W_z (fp32 [k][n]) to bf16 WT[z][n][k]
//       z==3 -> convert X fp32 -> bf16 (same layout)
// ---------------------------------------------------------------------------
__global__ __launch_bounds__(256) void prep(
    const float* __restrict__ X,
    const float* __restrict__ Wq, const float* __restrict__ Wk,
    const float* __restrict__ Wv,
    __bf16* __restrict__ Xb, __bf16* __restrict__ WT)
{
  const int z = blockIdx.z, t = threadIdx.x;
  if (z == 3) {
    size_t base = ((size_t)(blockIdx.y * 16 + blockIdx.x)) * 16384 + t * 4;
#pragma unroll
    for (int i = 0; i < 16; ++i) {
      size_t idx = base + (size_t)i * 1024;
      f32x4 v = *(const f32x4*)(X + idx);
      __bf16 o[4];
#pragma unroll
      for (int j = 0; j < 4; ++j) o[j] = (__bf16)v[j];
      *(ulong1*)(Xb + idx) = *(ulong1*)o;
    }
    return;
  }
  const float* W = (z == 0) ? Wq : (z == 1) ? Wk : Wv;
  __bf16* WTz = WT + (size_t)z * D_ * D_;
  const int k0 = blockIdx.y * 64, n0 = blockIdx.x * 64;

  __shared__ __bf16 T[64 * 72];
  {
    int kl = t >> 2, cg = (t & 3) * 16;
    const float* wp = W + (size_t)(k0 + kl) * D_ + n0 + cg;
    bf16x8 a, b;
#pragma unroll
    for (int j = 0; j < 4; ++j) { a[j] = (__bf16)wp[j];     a[4 + j] = (__bf16)wp[4 + j]; }
#pragma unroll
    for (int j = 0; j < 4; ++j) { b[j] = (__bf16)wp[8 + j]; b[4 + j] = (__bf16)wp[12 + j]; }
    *(bf16x8*)(T + kl * 72 + cg) = a;
    *(bf16x8*)(T + kl * 72 + cg + 8) = b;
  }
  __syncthreads();
  {
    int nl = t >> 2, kc = (t & 3) * 16;
    bf16x8 a, b;
#pragma unroll
    for (int j = 0; j < 8; ++j) a[j] = T[(kc + j) * 72 + nl];
#pragma unroll
    for (int j = 0; j < 8; ++j) b[j] = T[(kc + 8 + j) * 72 + nl];
    __bf16* op = WTz + (size_t)(n0 + nl) * D_ + k0 + kc;
    *(bf16x8*)(op) = a;
    *(bf16x8*)(op + 8) = b;
  }
}

// ---------------------------------------------------------------------------
// QKV projection (m97 structure + XOR-swizzled LDS, BK=32 — proven) with
// XCD-aware block swizzle (T1): round-robin dispatch sends the 8 blocks
// sharing an A-row-panel to 8 different XCDs -> each XCD refetches every
// panel (R7 counters: FETCH 68.7 MB vs ~14 ideal). Bijective remap
// swz=(lin&7)*32+lin>>3 (256%8==0) gives XCD k the blocks with by in
// [4k,4k+4): 1 MB Xb rows + 2 MB WT_z per XCD -> L2-resident. Pure index
// permutation: numerics unchanged.
//   z==0: Q (*0.125*log2e), z==1: K, z==2: V stored transposed VT[b][n][s]
// ---------------------------------------------------------------------------
__global__ __launch_bounds__(256) void qkv_gemm(
    const __bf16* __restrict__ Xb, const __bf16* __restrict__ WT,
    const float* __restrict__ bq, const float* __restrict__ bk,
    const float* __restrict__ bv,
    __bf16* __restrict__ Qw, __bf16* __restrict__ Kw, __bf16* __restrict__ VTw)
{
  const int z = blockIdx.z;
  const __bf16* Wz = WT + (size_t)z * D_ * D_;
  const float* bias = (z == 0) ? bq : (z == 1) ? bk : bv;
  __bf16* outp = (z == 0) ? Qw : (z == 1) ? Kw : VTw;
  const float mult = (z == 0) ? 0.125f * 1.44269504088896f : 1.0f;

  const int tid  = threadIdx.x;
  const int wave = tid >> 6, lane = tid & 63, ln = lane & 15, quad = lane >> 4;

  // XCD-aware swizzle of the 256 (bx,by) blocks per z (bijective)
  const int lin = blockIdx.x + 8 * blockIdx.y;     // 0..255, xcd = lin & 7
  const int swz = (lin & 7) * 32 + (lin >> 3);     // XCD k -> by in [4k,4k+4)
  const int m0 = (swz >> 3) * 128, n0 = (swz & 7) * 128;
  const int wm = (wave & 1) * 64, wn = (wave >> 1) * 64;

  __shared__ __bf16 Als[128 * 32];
  __shared__ __bf16 Bls[128 * 32];

  f32x4 acc[4][4] = {};

  for (int k0 = 0; k0 < D_; k0 += 32) {
    __syncthreads();
#pragma unroll
    for (int i = 0; i < 2; ++i) {
      int cb = wave * 128 + i * 64;          // wave-uniform chunk base
      int chunk = cb + lane;
      int row = chunk >> 2, c = chunk & 3;
      int gc = c ^ (row & 3);                // swizzled global source chunk
      load_lds16(Xb + (size_t)(m0 + row) * D_ + k0 + gc * 8, Als + cb * 8);
      load_lds16(Wz + (size_t)(n0 + row) * D_ + k0 + gc * 8, Bls + cb * 8);
    }
    __syncthreads();

    bf16x8 af[4], bfr[4];
    const int dsw = (quad ^ (ln & 3)) * 8;   // de-swizzle (row&3 == ln&3)
#pragma unroll
    for (int mt = 0; mt < 4; ++mt)
      af[mt] = *(const bf16x8*)(Als + (wm + mt * 16 + ln) * 32 + dsw);
#pragma unroll
    for (int nt = 0; nt < 4; ++nt)
      bfr[nt] = *(const bf16x8*)(Bls + (wn + nt * 16 + ln) * 32 + dsw);
#pragma unroll
    for (int mt = 0; mt < 4; ++mt)
#pragma unroll
      for (int nt = 0; nt < 4; ++nt)
        acc[mt][nt] = __builtin_amdgcn_mfma_f32_16x16x32_bf16(af[mt], bfr[nt], acc[mt][nt], 0, 0, 0);
  }

#pragma unroll
  for (int nt = 0; nt < 4; ++nt) {
    int n_g = n0 + wn + nt * 16 + ln;
    float bv_ = bias[n_g];
#pragma unroll
    for (int mt = 0; mt < 4; ++mt) {
      if (z < 2) {
#pragma unroll
        for (int r = 0; r < 4; ++r) {
          int m_g = m0 + wm + mt * 16 + quad * 4 + r;
          outp[(size_t)m_g * D_ + n_g] = (__bf16)((acc[mt][nt][r] + bv_) * mult);
        }
      } else {
        // VT[b][n][s]: pack r (4 consecutive s) into one b64 store
        int m_g0 = m0 + wm + mt * 16 + quad * 4;
        bf16x4 v4;
#pragma unroll
        for (int r = 0; r < 4; ++r) v4[r] = (__bf16)(acc[mt][nt][r] + bv_);
        *(bf16x4*)(outp + (size_t)(m_g0 >> 11) * D_ * S_ + (size_t)n_g * S_ + (m_g0 & (S_ - 1))) = v4;
      }
    }
  }
}

// ---------------------------------------------------------------------------
// Flash attention v8 (R4, proven 45.0 us — FROZEN): reg-prefetch staging
// (depth 1; depth 2 regressed to 70 us in R10), XOR-swizzled K/V LDS, single
// barrier/tile, lagged PV (PV(t-1) inside QK(t)'s MFMA cluster from register
// banks), in-register permlane P reshuffle, unnormalized exp2 softmax with
// MFMA row-sums (ones B-operand in regs).
// Sync/tiling edits all failed or regressed: R5 (gload pairing, race),
// R8 (QBLK=64, numerics), R9 (barrier pairing, numerics), R10 (prefetch
// depth 2, -55%). Do not perturb this schedule.
// ---------------------------------------------------------------------------
__global__ __launch_bounds__(256) void attn(
    const __bf16* __restrict__ Q, const __bf16* __restrict__ K,
    const __bf16* __restrict__ VT, float* __restrict__ out)
{
  const int tid  = threadIdx.x;
  const int wave = tid >> 6, lane = tid & 63, ln = lane & 15, quad = lane >> 4;

  const int f = blockIdx.x;
  const int xcd = f & 7, g = f >> 3;
  const int bh = ((g & 3) << 3) | xcd;   // 4 bh per XCD -> K/V L2-resident
  const int qt = g >> 2;                 // 0..15
  const int b = bh >> 4, h = bh & 15;
  const int q0 = qt * 128 + wave * 32;

  // Q B-frags (regs for whole kernel): lane n=ln -> q row, k = ks*32+quad*8+j
  const __bf16* Qbase = Q + (size_t)(b * S_ + q0) * D_ + h * HD_;
  bf16x8 qb[2][2];
#pragma unroll
  for (int nt = 0; nt < 2; ++nt)
#pragma unroll
    for (int ks = 0; ks < 2; ++ks)
      qb[nt][ks] = *(const bf16x8*)(Qbase + (size_t)(nt * 16 + ln) * D_ + ks * 32 + quad * 8);

  const __bf16* Kh = K + (size_t)b * S_ * D_ + h * HD_;        // [key][d]
  const __bf16* Vh = VT + (size_t)(b * D_ + h * HD_) * S_;     // [d][s]

  __shared__ __bf16 Kls[2][64 * 64];   // [key][d], swizzled chunks
  __shared__ __bf16 Vls[2][64 * 64];   // [d][key], swizzled chunks

  bf16x8 vones;
#pragma unroll
  for (int j = 0; j < 8; ++j) vones[j] = (__bf16)1.0f;

  f32x4 acc[2][5] = {};                // [q-block][d-tile 0..3, 4 = row-sum]
  const int swl = ln & 7;              // read-side swizzle key

  // prefetch tile 0 (2 chunks K + 2 chunks V per thread)
  bf16x8 kreg[2], vreg[2];
#pragma unroll
  for (int i = 0; i < 2; ++i) {
    int chunk = i * 256 + tid, row = chunk >> 3, cc = chunk & 7;
    kreg[i] = *(const bf16x8*)(Kh + (size_t)row * D_ + cc * 8);
    vreg[i] = *(const bf16x8*)(Vh + (size_t)row * S_ + cc * 8);
  }

  bf16x8 vfrA[4][2], vfrB[4][2];       // V frag banks (register)
  bf16x8 paA[2][2], paB[2][2];         // P A-frag banks (register)

  // one pipeline slot: stage tile KT_, prefetch KT_+1, barrier, hoist V(KT_)
  // frags into bank VN, QK(KT_) -> st, PV(KT_-1) from {PAP, VP}, exp2 -> PAN
#define SLOT(KT_, VN, VP, PAN, PAP, DO_PV)                                     \
  {                                                                            \
    const int bi = (KT_) & 1;                                                  \
    __bf16* Kb = Kls[bi];                                                      \
    __bf16* Vb = Vls[bi];                                                      \
    _Pragma("unroll")                                                          \
    for (int i = 0; i < 2; ++i) {                                              \
      int chunk = i * 256 + tid, row = chunk >> 3, cc = chunk & 7;             \
      int sw = (cc ^ (row & 7)) * 8;                                           \
      *(bf16x8*)(Kb + row * 64 + sw) = kreg[i];                                \
      *(bf16x8*)(Vb + row * 64 + sw) = vreg[i];                                \
    }                                                                          \
    if ((KT_) + 1 < NT_) {                                                     \
      _Pragma("unroll")                                                        \
      for (int i = 0; i < 2; ++i) {                                            \
        int chunk = i * 256 + tid, row = chunk >> 3, cc = chunk & 7;           \
        kreg[i] = *(const bf16x8*)(Kh + (size_t)(((KT_) + 1) * 64 + row) * D_ + cc * 8); \
        vreg[i] = *(const bf16x8*)(Vh + (size_t)row * S_ + ((KT_) + 1) * 64 + cc * 8);   \
      }                                                                        \
    }                                                                          \
    __syncthreads();                                                           \
    _Pragma("unroll")                                                          \
    for (int dt = 0; dt < 4; ++dt)                                             \
      _Pragma("unroll")                                                        \
      for (int ks = 0; ks < 2; ++ks)                                           \
        VN[dt][ks] = *(const bf16x8*)(Vb + (dt * 16 + ln) * 64 + ((ks * 4 + quad) ^ swl) * 8); \
    f32x4 st[4][2] = {};                                                       \
    __builtin_amdgcn_s_setprio(1);                                             \
    _Pragma("unroll")                                                          \
    for (int mt = 0; mt < 4; ++mt)                                             \
      _Pragma("unroll")                                                        \
      for (int ks = 0; ks < 2; ++ks) {                                         \
        bf16x8 ka = *(const bf16x8*)(Kb + (mt * 16 + ln) * 64 + ((ks * 4 + quad) ^ swl) * 8); \
        _Pragma("unroll")                                                      \
        for (int nt = 0; nt < 2; ++nt)                                         \
          st[mt][nt] = __builtin_amdgcn_mfma_f32_16x16x32_bf16(ka, qb[nt][ks], st[mt][nt], 0, 0, 0); \
      }                                                                        \
    if (DO_PV) {                                                               \
      _Pragma("unroll")                                                        \
      for (int ks = 0; ks < 2; ++ks)                                           \
        _Pragma("unroll")                                                      \
        for (int dt = 0; dt < 5; ++dt) {                                       \
          bf16x8 vb = (dt < 4) ? VP[dt][ks] : vones;                           \
          _Pragma("unroll")                                                    \
          for (int nt = 0; nt < 2; ++nt)                                       \
            acc[nt][dt] = __builtin_amdgcn_mfma_f32_16x16x32_bf16(PAP[nt][ks], vb, acc[nt][dt], 0, 0, 0); \
        }                                                                      \
    }                                                                          \
    __builtin_amdgcn_s_setprio(0);                                             \
    _Pragma("unroll")                                                          \
    for (int nt = 0; nt < 2; ++nt)                                             \
      _Pragma("unroll")                                                        \
      for (int ks = 0; ks < 2; ++ks) {                                         \
        bf16x4 p0, p1;                                                         \
        _Pragma("unroll")                                                      \
        for (int r = 0; r < 4; ++r) {                                          \
          p0[r] = (__bf16)__builtin_amdgcn_exp2f(st[2 * ks + 0][nt][r]);       \
          p1[r] = (__bf16)__builtin_amdgcn_exp2f(st[2 * ks + 1][nt][r]);       \
        }                                                                      \
        u32x2 d0 = __builtin_bit_cast(u32x2, p0);                              \
        u32x2 d1 = __builtin_bit_cast(u32x2, p1);                              \
        unsigned a = d0[0], bw = d0[1], c = d1[0], e = d1[1];                  \
        asm("v_permlane32_swap_b32 %0, %1" : "+v"(a), "+v"(c));                \
        asm("v_permlane16_swap_b32 %0, %1" : "+v"(a), "+v"(c));                \
        asm("v_permlane32_swap_b32 %0, %1" : "+v"(bw), "+v"(e));               \
        asm("v_permlane16_swap_b32 %0, %1" : "+v"(bw), "+v"(e));               \
        u32x4 w;                                                               \
        w[0] = a; w[1] = bw; w[2] = c; w[3] = e;                               \
        PAN[nt][ks] = __builtin_bit_cast(bf16x8, w);                           \
      }                                                                        \
  }

  for (int kt = 0; kt < NT_; kt += 2) {
    SLOT(kt,     vfrA, vfrB, paA, paB, kt > 0);   // PV(kt-1) from B banks
    SLOT(kt + 1, vfrB, vfrA, paB, paA, 1);        // PV(kt)   from A banks
  }
#undef SLOT

  // drain: PV for tile NT_-1 (banks B)
#pragma unroll
  for (int ks = 0; ks < 2; ++ks)
#pragma unroll
    for (int dt = 0; dt < 5; ++dt) {
      bf16x8 vb = (dt < 4) ? vfrB[dt][ks] : vones;
#pragma unroll
      for (int nt = 0; nt < 2; ++nt)
        acc[nt][dt] = __builtin_amdgcn_mfma_f32_16x16x32_bf16(paB[nt][ks], vb, acc[nt][dt], 0, 0, 0);
    }

  // acc[nt][4][r] = row sum (identical across ln); normalize + store fp32
#pragma unroll
  for (int nt = 0; nt < 2; ++nt)
#pragma unroll
    for (int r = 0; r < 4; ++r) {
      float li = 1.0f / acc[nt][4][r];
      float* op = out + (size_t)(b * S_ + q0 + nt * 16 + quad * 4 + r) * D_ + h * HD_;
#pragma unroll
      for (int dt = 0; dt < 4; ++dt)
        op[dt * 16 + ln] = acc[nt][dt][r] * li;
    }
}

extern "C" void kernel_launch(void* const* d_in, const int* in_sizes, int n_in,
                              void* d_out, int out_size, void* d_ws, size_t ws_size,
                              hipStream_t stream) {
  const float* X  = (const float*)d_in[0];
  const float* Wq = (const float*)d_in[1];
  const float* bq = (const float*)d_in[2];
  const float* Wk = (const float*)d_in[3];
  const float* bk = (const float*)d_in[4];
  const float* Wv = (const float*)d_in[5];
  const float* bv = (const float*)d_in[6];

  __bf16* Qw  = (__bf16*)d_ws;                        // 8 MB
  __bf16* Kw  = Qw  + (size_t)B_ * S_ * D_;           // 8 MB
  __bf16* VTw = Kw  + (size_t)B_ * S_ * D_;           // 8 MB
  __bf16* Xb  = VTw + (size_t)B_ * S_ * D_;           // 8 MB
  __bf16* WT  = Xb  + (size_t)B_ * S_ * D_;           // 6 MB
  float* out = (float*)d_out;

  prep<<<dim3(16, 16, 4), 256, 0, stream>>>(X, Wq, Wk, Wv, Xb, WT);
  qkv_gemm<<<dim3(8, 32, 3), 256, 0, stream>>>(Xb, WT, bq, bk, bv, Qw, Kw, VTw);
  attn<<<512, 256, 0, stream>>>(Qw, Kw, VTw, out);
}